// Round 1
// baseline (1007.798 us; speedup 1.0000x reference)
//
#include <hip/hip_runtime.h>

#define HW 4096
#define CCH 256
#define IC 128

static __device__ __forceinline__ float4 ld4(const float* p) {
  return *reinterpret_cast<const float4*>(p);
}
static __device__ __forceinline__ void st4(float* p, float4 v) {
  *reinterpret_cast<float4*>(p) = v;
}

#define FMA4(ACC, A, B)                                          \
  ACC = fmaf((A).x, (B).x, ACC); ACC = fmaf((A).y, (B).y, ACC);  \
  ACC = fmaf((A).z, (B).z, ACC); ACC = fmaf((A).w, (B).w, ACC);

// ---------------------------------------------------------------------------
// 1x1 conv -> pixel-major projection: out[n][p][128] = sum_c in[n][c][p]*w[o][c]+b[o]
// grid (64, 4), 256 threads
__global__ __launch_bounds__(256) void k_proj(const float* __restrict__ in,
                                              const float* __restrict__ w,
                                              const float* __restrict__ bias,
                                              float* __restrict__ out) {
  const int n = blockIdx.y;
  const int p0 = blockIdx.x * 64;
  const float* inN = in + (size_t)n * CCH * HW;
  __shared__ float sIn[16][68];
  __shared__ float sW[16][132];
  const int tid = threadIdx.x;
  const int tp = tid & 15, to = tid >> 4;
  float acc[4][8];
#pragma unroll
  for (int i = 0; i < 4; ++i)
#pragma unroll
    for (int j = 0; j < 8; ++j) acc[i][j] = 0.f;

  for (int c0 = 0; c0 < CCH; c0 += 16) {
    __syncthreads();
    {  // stage input tile [16 c][64 p]
      int cc = tid >> 4, p4 = tid & 15;
      st4(&sIn[cc][p4 * 4], ld4(&inN[(size_t)(c0 + cc) * HW + p0 + p4 * 4]));
    }
#pragma unroll
    for (int i = 0; i < 2; ++i) {  // stage weights transposed: sW[cc][o]
      int e4 = tid + 256 * i;
      int o = e4 >> 2, c4 = e4 & 3;
      float4 wv = ld4(&w[(size_t)o * CCH + c0 + c4 * 4]);
      sW[c4 * 4 + 0][o] = wv.x;
      sW[c4 * 4 + 1][o] = wv.y;
      sW[c4 * 4 + 2][o] = wv.z;
      sW[c4 * 4 + 3][o] = wv.w;
    }
    __syncthreads();
#pragma unroll
    for (int kk = 0; kk < 16; ++kk) {
      float4 bv = ld4(&sIn[kk][tp * 4]);
      float4 a0 = ld4(&sW[kk][to * 8]);
      float4 a1 = ld4(&sW[kk][to * 8 + 4]);
      float bb[4] = {bv.x, bv.y, bv.z, bv.w};
      float aa[8] = {a0.x, a0.y, a0.z, a0.w, a1.x, a1.y, a1.z, a1.w};
#pragma unroll
      for (int i = 0; i < 4; ++i)
#pragma unroll
        for (int j = 0; j < 8; ++j) acc[i][j] = fmaf(bb[i], aa[j], acc[i][j]);
    }
  }
  float bs[8];
#pragma unroll
  for (int j = 0; j < 8; ++j) bs[j] = bias[to * 8 + j];
  float* dst = out + ((size_t)n * HW + p0) * IC;
#pragma unroll
  for (int i = 0; i < 4; ++i) {
    float4 v0 = make_float4(acc[i][0] + bs[0], acc[i][1] + bs[1],
                            acc[i][2] + bs[2], acc[i][3] + bs[3]);
    float4 v1 = make_float4(acc[i][4] + bs[4], acc[i][5] + bs[5],
                            acc[i][6] + bs[6], acc[i][7] + bs[7]);
    st4(&dst[(size_t)(tp * 4 + i) * IC + to * 8], v0);
    st4(&dst[(size_t)(tp * 4 + i) * IC + to * 8 + 4], v1);
  }
}

// ---------------------------------------------------------------------------
// scores: E = exp(theta . phi / sqrt(128)) -> P (unnormalized), rowsum per q row.
// grid (64, 4): each wg owns 64 q rows over all 4096 k. 256 threads.
__global__ __launch_bounds__(256) void k_scores(const float* __restrict__ th,
                                                const float* __restrict__ ph,
                                                float* __restrict__ P,
                                                float* __restrict__ rowsum) {
  const int n = blockIdx.y;
  const int q0 = blockIdx.x * 64;
  __shared__ float sTh[64][132];
  __shared__ float sPh[64][132];
  __shared__ float sRed[64][17];
  const int tid = threadIdx.x;
  const int tx = tid & 15, ty = tid >> 4;
  {
    const float* src = th + ((size_t)n * HW + q0) * IC;
#pragma unroll
    for (int i = 0; i < 8; ++i) {
      int e4 = tid + 256 * i;
      int row = e4 >> 5, c4 = e4 & 31;
      st4(&sTh[row][c4 * 4], ld4(&src[(size_t)row * IC + c4 * 4]));
    }
  }
  float rs[4] = {0.f, 0.f, 0.f, 0.f};
  const float scale = 0.08838834764831845f;  // 1/sqrt(128)
  for (int k0 = 0; k0 < HW; k0 += 64) {
    __syncthreads();
    {
      const float* src = ph + ((size_t)n * HW + k0) * IC;
#pragma unroll
      for (int i = 0; i < 8; ++i) {
        int e4 = tid + 256 * i;
        int row = e4 >> 5, c4 = e4 & 31;
        st4(&sPh[row][c4 * 4], ld4(&src[(size_t)row * IC + c4 * 4]));
      }
    }
    __syncthreads();
    float acc[4][4] = {};
#pragma unroll 4
    for (int kk = 0; kk < 32; ++kk) {
      float4 a0 = ld4(&sTh[ty * 4 + 0][kk * 4]);
      float4 a1 = ld4(&sTh[ty * 4 + 1][kk * 4]);
      float4 a2 = ld4(&sTh[ty * 4 + 2][kk * 4]);
      float4 a3 = ld4(&sTh[ty * 4 + 3][kk * 4]);
      float4 b0 = ld4(&sPh[tx + 0][kk * 4]);
      float4 b1 = ld4(&sPh[tx + 16][kk * 4]);
      float4 b2 = ld4(&sPh[tx + 32][kk * 4]);
      float4 b3 = ld4(&sPh[tx + 48][kk * 4]);
      FMA4(acc[0][0], a0, b0) FMA4(acc[0][1], a0, b1) FMA4(acc[0][2], a0, b2) FMA4(acc[0][3], a0, b3)
      FMA4(acc[1][0], a1, b0) FMA4(acc[1][1], a1, b1) FMA4(acc[1][2], a1, b2) FMA4(acc[1][3], a1, b3)
      FMA4(acc[2][0], a2, b0) FMA4(acc[2][1], a2, b1) FMA4(acc[2][2], a2, b2) FMA4(acc[2][3], a2, b3)
      FMA4(acc[3][0], a3, b0) FMA4(acc[3][1], a3, b1) FMA4(acc[3][2], a3, b2) FMA4(acc[3][3], a3, b3)
    }
#pragma unroll
    for (int i = 0; i < 4; ++i) {
      float* prow = &P[((size_t)n * HW + q0 + ty * 4 + i) * HW + k0];
      float e0 = __expf(acc[i][0] * scale);
      float e1 = __expf(acc[i][1] * scale);
      float e2 = __expf(acc[i][2] * scale);
      float e3 = __expf(acc[i][3] * scale);
      prow[tx] = e0;
      prow[tx + 16] = e1;
      prow[tx + 32] = e2;
      prow[tx + 48] = e3;
      rs[i] += (e0 + e1) + (e2 + e3);
    }
  }
#pragma unroll
  for (int i = 0; i < 4; ++i) sRed[ty * 4 + i][tx] = rs[i];
  __syncthreads();
  if (tid < 64) {
    float s = 0.f;
#pragma unroll
    for (int j = 0; j < 16; ++j) s += sRed[tid][j];
    rowsum[(size_t)n * HW + q0 + tid] = s;
  }
}

// ---------------------------------------------------------------------------
// pv: normalize P in place (E/rowsum) and y[q][ic] = sum_k P[q,k]*g[k][ic]
// grid (64, 4), 256 threads
__global__ __launch_bounds__(256) void k_pv(float* __restrict__ P,
                                            const float* __restrict__ rowsum,
                                            const float* __restrict__ g,
                                            float* __restrict__ yT) {
  const int n = blockIdx.y;
  const int q0 = blockIdx.x * 64;
  __shared__ float sP[64][68];
  __shared__ float sG[64][132];
  const int tid = threadIdx.x;
  const int tx = tid & 15, ty = tid >> 4;
  float inv[4];
#pragma unroll
  for (int i = 0; i < 4; ++i)
    inv[i] = 1.f / rowsum[(size_t)n * HW + q0 + ty * 4 + i];
  float acc[4][8];
#pragma unroll
  for (int i = 0; i < 4; ++i)
#pragma unroll
    for (int j = 0; j < 8; ++j) acc[i][j] = 0.f;

  for (int k0 = 0; k0 < HW; k0 += 64) {
    __syncthreads();
#pragma unroll
    for (int i = 0; i < 4; ++i) {
      size_t addr = ((size_t)n * HW + q0 + ty * 4 + i) * HW + k0 + tx * 4;
      float4 e = ld4(&P[addr]);
      e.x *= inv[i]; e.y *= inv[i]; e.z *= inv[i]; e.w *= inv[i];
      st4(&P[addr], e);
      st4(&sP[ty * 4 + i][tx * 4], e);
    }
    {
      const float* src = g + ((size_t)n * HW + k0) * IC;
#pragma unroll
      for (int i = 0; i < 8; ++i) {
        int e4 = tid + 256 * i;
        int row = e4 >> 5, c4 = e4 & 31;
        st4(&sG[row][c4 * 4], ld4(&src[(size_t)row * IC + c4 * 4]));
      }
    }
    __syncthreads();
#pragma unroll 8
    for (int kk = 0; kk < 64; ++kk) {
      float a0 = sP[ty * 4 + 0][kk];
      float a1 = sP[ty * 4 + 1][kk];
      float a2 = sP[ty * 4 + 2][kk];
      float a3 = sP[ty * 4 + 3][kk];
      float4 b0 = ld4(&sG[kk][tx * 8]);
      float4 b1 = ld4(&sG[kk][tx * 8 + 4]);
      float bv[8] = {b0.x, b0.y, b0.z, b0.w, b1.x, b1.y, b1.z, b1.w};
#pragma unroll
      for (int j = 0; j < 8; ++j) {
        acc[0][j] = fmaf(a0, bv[j], acc[0][j]);
        acc[1][j] = fmaf(a1, bv[j], acc[1][j]);
        acc[2][j] = fmaf(a2, bv[j], acc[2][j]);
        acc[3][j] = fmaf(a3, bv[j], acc[3][j]);
      }
    }
  }
  float* dst = yT + ((size_t)n * HW + q0) * IC;
#pragma unroll
  for (int i = 0; i < 4; ++i) {
    st4(&dst[(size_t)(ty * 4 + i) * IC + tx * 8],
        make_float4(acc[i][0], acc[i][1], acc[i][2], acc[i][3]));
    st4(&dst[(size_t)(ty * 4 + i) * IC + tx * 8 + 4],
        make_float4(acc[i][4], acc[i][5], acc[i][6], acc[i][7]));
  }
}

// ---------------------------------------------------------------------------
// out conv: y2[n][o][p] = sum_ic out_w[o][ic]*yT[n][p][ic] + b[o]
// grid (256, 4): bx = pblk(64) | oblk(4)<<6
__global__ __launch_bounds__(256) void k_outconv(const float* __restrict__ yT,
                                                 const float* __restrict__ w,
                                                 const float* __restrict__ bias,
                                                 float* __restrict__ y2) {
  const int n = blockIdx.y;
  const int p0 = (blockIdx.x & 63) * 64;
  const int o0 = (blockIdx.x >> 6) * 64;
  __shared__ float sY[64][132];
  __shared__ float sW[64][132];
  const int tid = threadIdx.x;
  const int tx = tid & 15, ty = tid >> 4;
  {
    const float* src = yT + ((size_t)n * HW + p0) * IC;
    const float* srcw = w + (size_t)o0 * IC;
#pragma unroll
    for (int i = 0; i < 8; ++i) {
      int e4 = tid + 256 * i;
      int row = e4 >> 5, c4 = e4 & 31;
      st4(&sY[row][c4 * 4], ld4(&src[(size_t)row * IC + c4 * 4]));
      st4(&sW[row][c4 * 4], ld4(&srcw[(size_t)row * IC + c4 * 4]));
    }
  }
  __syncthreads();
  float acc[4][4] = {};
#pragma unroll 4
  for (int kk = 0; kk < 32; ++kk) {
    float4 a0 = ld4(&sY[tx + 0][kk * 4]);
    float4 a1 = ld4(&sY[tx + 16][kk * 4]);
    float4 a2 = ld4(&sY[tx + 32][kk * 4]);
    float4 a3 = ld4(&sY[tx + 48][kk * 4]);
    float4 b0 = ld4(&sW[ty * 4 + 0][kk * 4]);
    float4 b1 = ld4(&sW[ty * 4 + 1][kk * 4]);
    float4 b2 = ld4(&sW[ty * 4 + 2][kk * 4]);
    float4 b3 = ld4(&sW[ty * 4 + 3][kk * 4]);
    FMA4(acc[0][0], a0, b0) FMA4(acc[0][1], a0, b1) FMA4(acc[0][2], a0, b2) FMA4(acc[0][3], a0, b3)
    FMA4(acc[1][0], a1, b0) FMA4(acc[1][1], a1, b1) FMA4(acc[1][2], a1, b2) FMA4(acc[1][3], a1, b3)
    FMA4(acc[2][0], a2, b0) FMA4(acc[2][1], a2, b1) FMA4(acc[2][2], a2, b2) FMA4(acc[2][3], a2, b3)
    FMA4(acc[3][0], a3, b0) FMA4(acc[3][1], a3, b1) FMA4(acc[3][2], a3, b2) FMA4(acc[3][3], a3, b3)
  }
#pragma unroll
  for (int j = 0; j < 4; ++j) {
    float bb = bias[o0 + ty * 4 + j];
    float* dst = &y2[((size_t)n * CCH + o0 + ty * 4 + j) * HW + p0];
#pragma unroll
    for (int i = 0; i < 4; ++i) dst[tx + 16 * i] = acc[i][j] + bb;
  }
}

// ---------------------------------------------------------------------------
// c1: coef1[n][o][p] = relu(sum_{k<512} c1_w[o][k]*cat[k][p] + b[o]),
// cat = [x(256ch); y2(256ch)].  grid (256, 4): bx = pblk(64) | oblk(4)<<6
__global__ __launch_bounds__(256) void k_c1(const float* __restrict__ x,
                                            const float* __restrict__ y2,
                                            const float* __restrict__ w,
                                            const float* __restrict__ bias,
                                            float* __restrict__ coef1) {
  const int n = blockIdx.y;
  const int p0 = (blockIdx.x & 63) * 64;
  const int o0 = (blockIdx.x >> 6) * 64;
  __shared__ float sIn[16][68];
  __shared__ float sW[16][68];
  const int tid = threadIdx.x;
  const int tx = tid & 15, ty = tid >> 4;
  float acc[4][4] = {};
  for (int c0 = 0; c0 < 512; c0 += 16) {
    __syncthreads();
    const float* src = (c0 < 256)
                           ? (x + (size_t)n * CCH * HW + (size_t)c0 * HW)
                           : (y2 + (size_t)n * CCH * HW + (size_t)(c0 - 256) * HW);
    {
      int cc = tid >> 4, p4 = tid & 15;
      st4(&sIn[cc][p4 * 4], ld4(&src[(size_t)cc * HW + p0 + p4 * 4]));
    }
    {
      int o = tid >> 2, c4 = tid & 3;
      float4 wv = ld4(&w[(size_t)(o0 + o) * 512 + c0 + c4 * 4]);
      sW[c4 * 4 + 0][o] = wv.x;
      sW[c4 * 4 + 1][o] = wv.y;
      sW[c4 * 4 + 2][o] = wv.z;
      sW[c4 * 4 + 3][o] = wv.w;
    }
    __syncthreads();
#pragma unroll
    for (int kk = 0; kk < 16; ++kk) {
      float4 bv = ld4(&sIn[kk][tx * 4]);
      float4 av = ld4(&sW[kk][ty * 4]);
      float bb[4] = {bv.x, bv.y, bv.z, bv.w};
      float aa[4] = {av.x, av.y, av.z, av.w};
#pragma unroll
      for (int i = 0; i < 4; ++i)
#pragma unroll
        for (int j = 0; j < 4; ++j) acc[i][j] = fmaf(bb[i], aa[j], acc[i][j]);
    }
  }
#pragma unroll
  for (int j = 0; j < 4; ++j) {
    float bb = bias[o0 + ty * 4 + j];
    float4 v = make_float4(fmaxf(acc[0][j] + bb, 0.f), fmaxf(acc[1][j] + bb, 0.f),
                           fmaxf(acc[2][j] + bb, 0.f), fmaxf(acc[3][j] + bb, 0.f));
    st4(&coef1[((size_t)n * CCH + o0 + ty * 4 + j) * HW + p0 + tx * 4], v);
  }
}

// ---------------------------------------------------------------------------
// c2 partials over 64-channel chunks: grid (16, 4, 4), thread = pixel
__global__ __launch_bounds__(256) void k_c2p(const float* __restrict__ coef1,
                                             const float* __restrict__ w,
                                             float* __restrict__ part) {
  const int n = blockIdx.y;
  const int kc = blockIdx.z;
  const int p = blockIdx.x * 256 + threadIdx.x;
  const int px = p & 63, py = p >> 6;
  float acc[16];
#pragma unroll
  for (int o = 0; o < 16; ++o) acc[o] = 0.f;
  const float* base = coef1 + (size_t)n * CCH * HW + (size_t)kc * 64 * HW;
  for (int c = 0; c < 64; ++c) {
    const float* img = base + (size_t)c * HW;
    float v[9];
#pragma unroll
    for (int dy = -1; dy <= 1; ++dy)
#pragma unroll
      for (int dx = -1; dx <= 1; ++dx) {
        int yy = py + dy, xx = px + dx;
        bool ok = ((unsigned)yy < 64u) && ((unsigned)xx < 64u);
        v[(dy + 1) * 3 + dx + 1] = ok ? img[yy * 64 + xx] : 0.f;
      }
    const int cg = kc * 64 + c;
#pragma unroll
    for (int o = 0; o < 16; ++o) {
      const float* wp = w + ((size_t)o * CCH + cg) * 9;
      float a = acc[o];
      a = fmaf(wp[0], v[0], a); a = fmaf(wp[1], v[1], a); a = fmaf(wp[2], v[2], a);
      a = fmaf(wp[3], v[3], a); a = fmaf(wp[4], v[4], a); a = fmaf(wp[5], v[5], a);
      a = fmaf(wp[6], v[6], a); a = fmaf(wp[7], v[7], a); a = fmaf(wp[8], v[8], a);
      acc[o] = a;
    }
  }
  float* dst = part + (((size_t)kc * 4 + n) * 16) * HW + p;
#pragma unroll
  for (int o = 0; o < 16; ++o) dst[(size_t)o * HW] = acc[o];
}

// c2 reduce + bias + relu: grid (16, 4)
__global__ __launch_bounds__(256) void k_c2r(const float* __restrict__ part,
                                             const float* __restrict__ bias,
                                             float* __restrict__ c2o) {
  const int n = blockIdx.y;
  const int p = blockIdx.x * 256 + threadIdx.x;
#pragma unroll
  for (int o = 0; o < 16; ++o) {
    float s = bias[o];
#pragma unroll
    for (int kc = 0; kc < 4; ++kc)
      s += part[(((size_t)kc * 4 + n) * 16 + o) * HW + p];
    c2o[((size_t)n * 16 + o) * HW + p] = fmaxf(s, 0.f);
  }
}

// ---------------------------------------------------------------------------
// c3: 16 -> 3, 3x3, relu. grid (16, 4), thread = pixel
__global__ __launch_bounds__(256) void k_c3(const float* __restrict__ c2o,
                                            const float* __restrict__ w,
                                            const float* __restrict__ bias,
                                            float* __restrict__ c3o) {
  const int n = blockIdx.y;
  const int p = blockIdx.x * 256 + threadIdx.x;
  const int px = p & 63, py = p >> 6;
  float acc[3] = {bias[0], bias[1], bias[2]};
  for (int c = 0; c < 16; ++c) {
    const float* img = c2o + ((size_t)n * 16 + c) * HW;
    float v[9];
#pragma unroll
    for (int dy = -1; dy <= 1; ++dy)
#pragma unroll
      for (int dx = -1; dx <= 1; ++dx) {
        int yy = py + dy, xx = px + dx;
        bool ok = ((unsigned)yy < 64u) && ((unsigned)xx < 64u);
        v[(dy + 1) * 3 + dx + 1] = ok ? img[yy * 64 + xx] : 0.f;
      }
#pragma unroll
    for (int o = 0; o < 3; ++o) {
      const float* wp = w + ((size_t)o * 16 + c) * 9;
      float a = acc[o];
      a = fmaf(wp[0], v[0], a); a = fmaf(wp[1], v[1], a); a = fmaf(wp[2], v[2], a);
      a = fmaf(wp[3], v[3], a); a = fmaf(wp[4], v[4], a); a = fmaf(wp[5], v[5], a);
      a = fmaf(wp[6], v[6], a); a = fmaf(wp[7], v[7], a); a = fmaf(wp[8], v[8], a);
      acc[o] = a;
    }
  }
#pragma unroll
  for (int o = 0; o < 3; ++o)
    c3o[((size_t)n * 3 + o) * HW + p] = fmaxf(acc[o], 0.f);
}

// ---------------------------------------------------------------------------
// c4 (3->1, 3x3, no relu) + final output = x + coef*y2. grid (16, 4, 4 c-chunks)
__global__ __launch_bounds__(256) void k_c4f(const float* __restrict__ c3o,
                                             const float* __restrict__ w4,
                                             const float* __restrict__ b4,
                                             const float* __restrict__ x,
                                             const float* __restrict__ y2,
                                             float* __restrict__ out0) {
  const int n = blockIdx.y;
  const int cc = blockIdx.z;
  const int p = blockIdx.x * 256 + threadIdx.x;
  const int px = p & 63, py = p >> 6;
  float coef = b4[0];
#pragma unroll
  for (int c = 0; c < 3; ++c) {
    const float* img = c3o + ((size_t)n * 3 + c) * HW;
#pragma unroll
    for (int dy = -1; dy <= 1; ++dy)
#pragma unroll
      for (int dx = -1; dx <= 1; ++dx) {
        int yy = py + dy, xx = px + dx;
        bool ok = ((unsigned)yy < 64u) && ((unsigned)xx < 64u);
        float v = ok ? img[yy * 64 + xx] : 0.f;
        coef = fmaf(w4[c * 9 + (dy + 1) * 3 + dx + 1], v, coef);
      }
  }
  const size_t base = ((size_t)n * CCH + cc * 64) * HW + p;
#pragma unroll 8
  for (int c = 0; c < 64; ++c) {
    size_t a = base + (size_t)c * HW;
    out0[a] = x[a] + coef * y2[a];
  }
}

// ---------------------------------------------------------------------------
extern "C" void kernel_launch(void* const* d_in, const int* in_sizes, int n_in,
                              void* d_out, int out_size, void* d_ws, size_t ws_size,
                              hipStream_t stream) {
  (void)in_sizes; (void)n_in; (void)out_size; (void)ws_size;
  const float* x     = (const float*)d_in[0];
  const float* x_ref = (const float*)d_in[1];
  const float* g_w   = (const float*)d_in[2];
  const float* g_b   = (const float*)d_in[3];
  const float* th_w  = (const float*)d_in[4];
  const float* th_b  = (const float*)d_in[5];
  const float* ph_w  = (const float*)d_in[6];
  const float* ph_b  = (const float*)d_in[7];
  const float* out_w = (const float*)d_in[8];
  const float* out_b = (const float*)d_in[9];
  const float* c1_w  = (const float*)d_in[10];
  const float* c1_b  = (const float*)d_in[11];
  const float* c2_w  = (const float*)d_in[12];
  const float* c2_b  = (const float*)d_in[13];
  const float* c3_w  = (const float*)d_in[14];
  const float* c3_b  = (const float*)d_in[15];
  const float* c4_w  = (const float*)d_in[16];
  const float* c4_b  = (const float*)d_in[17];

  float* ws = (float*)d_ws;
  // region plan (floats):
  //   [0 .. 2M)   thetaT       -> later reused (with phiT) as y2
  //   [2M .. 4M)  phiT
  //   [4M .. 6M)  gT           -> later reused (with yT) as coef1
  //   [6M .. 8M)  yT
  float* thetaT = ws + 0;
  float* phiT   = ws + 2097152;
  float* gT     = ws + 4194304;
  float* yT     = ws + 6291456;
  float* y2     = ws + 0;        // 4,194,304 floats (aliases thetaT+phiT, dead then)
  float* coef1  = ws + 4194304;  // 4,194,304 floats (aliases gT+yT, dead then)
  float* rowsum = ws + 8388608;  // 16,384
  float* c2p    = ws + 8404992;  // 1,048,576
  float* c2o    = ws + 9453568;  // 262,144
  float* c3o    = ws + 9715712;  // 49,152  (total 9,764,864 floats = 39.1 MB)

  float* out0 = (float*)d_out;
  float* P    = out0 + 4194304;  // pairwise_weight region, also E scratch

  dim3 blk(256);
  k_proj<<<dim3(64, 4), blk, 0, stream>>>(x, th_w, th_b, thetaT);
  k_proj<<<dim3(64, 4), blk, 0, stream>>>(x_ref, ph_w, ph_b, phiT);
  k_proj<<<dim3(64, 4), blk, 0, stream>>>(x_ref, g_w, g_b, gT);
  k_scores<<<dim3(64, 4), blk, 0, stream>>>(thetaT, phiT, P, rowsum);
  k_pv<<<dim3(64, 4), blk, 0, stream>>>(P, rowsum, gT, yT);
  k_outconv<<<dim3(256, 4), blk, 0, stream>>>(yT, out_w, out_b, y2);
  k_c1<<<dim3(256, 4), blk, 0, stream>>>(x, y2, c1_w, c1_b, coef1);
  k_c2p<<<dim3(16, 4, 4), blk, 0, stream>>>(coef1, c2_w, c2p);
  k_c2r<<<dim3(16, 4), blk, 0, stream>>>(c2p, c2_b, c2o);
  k_c3<<<dim3(16, 4), blk, 0, stream>>>(c2o, c3_w, c3_b, c3o);
  k_c4f<<<dim3(16, 4, 4), blk, 0, stream>>>(c3o, c4_w, c4_b, x, y2, out0);
}

// Round 2
// 419.582 us; speedup vs baseline: 2.4019x; 2.4019x over previous
//
#include <hip/hip_runtime.h>

#define HW 4096
#define CCH 256
#define IC 128

typedef __bf16 bf16x8 __attribute__((ext_vector_type(8)));
typedef float f32x4 __attribute__((ext_vector_type(4)));

#define MFMA16(a, b, c) __builtin_amdgcn_mfma_f32_16x16x32_bf16(a, b, c, 0, 0, 0)

static __device__ __forceinline__ float4 ld4(const float* p) {
  return *reinterpret_cast<const float4*>(p);
}
static __device__ __forceinline__ void st4(float* p, float4 v) {
  *reinterpret_cast<float4*>(p) = v;
}

#define FMA4(ACC, A, B)                                          \
  ACC = fmaf((A).x, (B).x, ACC); ACC = fmaf((A).y, (B).y, ACC);  \
  ACC = fmaf((A).z, (B).z, ACC); ACC = fmaf((A).w, (B).w, ACC);

// ---------------------------------------------------------------------------
// 1x1 conv -> pixel-major bf16: out[n][p][128]  (theta, phi)
__global__ __launch_bounds__(256) void k_projA(const float* __restrict__ in,
                                               const float* __restrict__ w,
                                               const float* __restrict__ bias,
                                               __bf16* __restrict__ out) {
  const int n = blockIdx.y;
  const int p0 = blockIdx.x * 64;
  const float* inN = in + (size_t)n * CCH * HW;
  __shared__ float sIn[16][68];
  __shared__ float sW[16][132];
  const int tid = threadIdx.x;
  const int tp = tid & 15, to = tid >> 4;
  float acc[4][8];
#pragma unroll
  for (int i = 0; i < 4; ++i)
#pragma unroll
    for (int j = 0; j < 8; ++j) acc[i][j] = 0.f;

  for (int c0 = 0; c0 < CCH; c0 += 16) {
    __syncthreads();
    {
      int cc = tid >> 4, p4 = tid & 15;
      st4(&sIn[cc][p4 * 4], ld4(&inN[(size_t)(c0 + cc) * HW + p0 + p4 * 4]));
    }
#pragma unroll
    for (int i = 0; i < 2; ++i) {
      int e4 = tid + 256 * i;
      int o = e4 >> 2, c4 = e4 & 3;
      float4 wv = ld4(&w[(size_t)o * CCH + c0 + c4 * 4]);
      sW[c4 * 4 + 0][o] = wv.x;
      sW[c4 * 4 + 1][o] = wv.y;
      sW[c4 * 4 + 2][o] = wv.z;
      sW[c4 * 4 + 3][o] = wv.w;
    }
    __syncthreads();
#pragma unroll
    for (int kk = 0; kk < 16; ++kk) {
      float4 bv = ld4(&sIn[kk][tp * 4]);
      float4 a0 = ld4(&sW[kk][to * 8]);
      float4 a1 = ld4(&sW[kk][to * 8 + 4]);
      float bb[4] = {bv.x, bv.y, bv.z, bv.w};
      float aa[8] = {a0.x, a0.y, a0.z, a0.w, a1.x, a1.y, a1.z, a1.w};
#pragma unroll
      for (int i = 0; i < 4; ++i)
#pragma unroll
        for (int j = 0; j < 8; ++j) acc[i][j] = fmaf(bb[i], aa[j], acc[i][j]);
    }
  }
  float bs[8];
#pragma unroll
  for (int j = 0; j < 8; ++j) bs[j] = bias[to * 8 + j];
  __bf16* dst = out + ((size_t)n * HW + p0) * IC;
#pragma unroll
  for (int i = 0; i < 4; ++i) {
    bf16x8 v;
#pragma unroll
    for (int j = 0; j < 8; ++j) v[j] = (__bf16)(acc[i][j] + bs[j]);
    *reinterpret_cast<bf16x8*>(&dst[(size_t)(tp * 4 + i) * IC + to * 8]) = v;
  }
}

// ---------------------------------------------------------------------------
// 1x1 conv -> channel-major bf16: out[n][128][4096]  (g)
__global__ __launch_bounds__(256) void k_projG(const float* __restrict__ in,
                                               const float* __restrict__ w,
                                               const float* __restrict__ bias,
                                               __bf16* __restrict__ out) {
  const int n = blockIdx.y;
  const int p0 = blockIdx.x * 64;
  const float* inN = in + (size_t)n * CCH * HW;
  __shared__ float sIn[16][68];
  __shared__ float sW[16][132];
  __shared__ __attribute__((aligned(16))) __bf16 sT[128][72];
  const int tid = threadIdx.x;
  const int tp = tid & 15, to = tid >> 4;
  float acc[4][8];
#pragma unroll
  for (int i = 0; i < 4; ++i)
#pragma unroll
    for (int j = 0; j < 8; ++j) acc[i][j] = 0.f;

  for (int c0 = 0; c0 < CCH; c0 += 16) {
    __syncthreads();
    {
      int cc = tid >> 4, p4 = tid & 15;
      st4(&sIn[cc][p4 * 4], ld4(&inN[(size_t)(c0 + cc) * HW + p0 + p4 * 4]));
    }
#pragma unroll
    for (int i = 0; i < 2; ++i) {
      int e4 = tid + 256 * i;
      int o = e4 >> 2, c4 = e4 & 3;
      float4 wv = ld4(&w[(size_t)o * CCH + c0 + c4 * 4]);
      sW[c4 * 4 + 0][o] = wv.x;
      sW[c4 * 4 + 1][o] = wv.y;
      sW[c4 * 4 + 2][o] = wv.z;
      sW[c4 * 4 + 3][o] = wv.w;
    }
    __syncthreads();
#pragma unroll
    for (int kk = 0; kk < 16; ++kk) {
      float4 bv = ld4(&sIn[kk][tp * 4]);
      float4 a0 = ld4(&sW[kk][to * 8]);
      float4 a1 = ld4(&sW[kk][to * 8 + 4]);
      float bb[4] = {bv.x, bv.y, bv.z, bv.w};
      float aa[8] = {a0.x, a0.y, a0.z, a0.w, a1.x, a1.y, a1.z, a1.w};
#pragma unroll
      for (int i = 0; i < 4; ++i)
#pragma unroll
        for (int j = 0; j < 8; ++j) acc[i][j] = fmaf(bb[i], aa[j], acc[i][j]);
    }
  }
  float bs[8];
#pragma unroll
  for (int j = 0; j < 8; ++j) bs[j] = bias[to * 8 + j];
  __syncthreads();
#pragma unroll
  for (int i = 0; i < 4; ++i)
#pragma unroll
    for (int j = 0; j < 8; ++j)
      sT[to * 8 + j][tp * 4 + i] = (__bf16)(acc[i][j] + bs[j]);
  __syncthreads();
  const int row = tid >> 1, half = tid & 1;
  __bf16* dst = out + (size_t)n * IC * HW + (size_t)row * HW + p0 + half * 32;
#pragma unroll
  for (int m = 0; m < 4; ++m)
    *reinterpret_cast<bf16x8*>(&dst[m * 8]) =
        *reinterpret_cast<const bf16x8*>(&sT[row][half * 32 + m * 8]);
}

// ---------------------------------------------------------------------------
// Fused attention: softmax(theta.phi^T/sqrt(128)) -> P (fp32, d_out) and
// yT[n][p][128] = P.g  (fp32).
// grid (64, 4), 512 threads = 8 waves: wave = (qg 0..3 [16 q rows], kh 0..1 [2048 k])
__global__ __launch_bounds__(512) void k_attn(const __bf16* __restrict__ thB,
                                              const __bf16* __restrict__ phB,
                                              const __bf16* __restrict__ gB,
                                              float* __restrict__ P,
                                              float* __restrict__ yT) {
  const int n = blockIdx.y;
  const int q0 = blockIdx.x * 64;
  const int tid = threadIdx.x;
  const int wv = tid >> 6;
  const int lane = tid & 63;
  const int qg = wv & 3;
  const int kh = wv >> 2;
  const int l15 = lane & 15;
  const int lg = lane >> 4;

  __shared__ __attribute__((aligned(16))) __bf16 sPhi[2][64][136];
  __shared__ __attribute__((aligned(16))) __bf16 sG[2][128][72];
  __shared__ __attribute__((aligned(16))) __bf16 sPb[8][16][72];
  __shared__ float sY[64][132];
  __shared__ float sRS[2][64];
  __shared__ float sInv[64];

  const __bf16* phN = phB + (size_t)n * HW * IC;
  const __bf16* gN = gB + (size_t)n * IC * HW;
  const float scale = 0.08838834764831845f;  // 1/sqrt(128)

  // persistent theta A-frags: row q = q0+qg*16+l15, c = lg*8 + 32*cj
  const __bf16* thRow = thB + ((size_t)n * HW + q0 + qg * 16 + l15) * IC + lg * 8;
  bf16x8 aQ[4];
#pragma unroll
  for (int cj = 0; cj < 4; ++cj)
    aQ[cj] = *reinterpret_cast<const bf16x8*>(thRow + 32 * cj);

  const int u = tid & 255;

  // ---------------- Phase A: rowsums ----------------
  float rs[4] = {0.f, 0.f, 0.f, 0.f};
  for (int k0 = kh * 2048, it = 0; it < 32; ++it, k0 += 64) {
    __syncthreads();
#pragma unroll
    for (int rep = 0; rep < 4; ++rep) {
      int row = (u >> 4) + rep * 16, seg = u & 15;
      *reinterpret_cast<bf16x8*>(&sPhi[kh][row][seg * 8]) =
          *reinterpret_cast<const bf16x8*>(&phN[(size_t)(k0 + row) * IC + seg * 8]);
    }
    __syncthreads();
    f32x4 cc[4] = {{0, 0, 0, 0}, {0, 0, 0, 0}, {0, 0, 0, 0}, {0, 0, 0, 0}};
#pragma unroll
    for (int kt = 0; kt < 4; ++kt)
#pragma unroll
      for (int cj = 0; cj < 4; ++cj) {
        bf16x8 b = *reinterpret_cast<const bf16x8*>(&sPhi[kh][kt * 16 + l15][cj * 32 + lg * 8]);
        cc[kt] = MFMA16(aQ[cj], b, cc[kt]);
      }
#pragma unroll
    for (int kt = 0; kt < 4; ++kt)
#pragma unroll
      for (int r = 0; r < 4; ++r) rs[r] += __expf(cc[kt][r] * scale);
  }
#pragma unroll
  for (int m = 1; m < 16; m <<= 1)
#pragma unroll
    for (int r = 0; r < 4; ++r) rs[r] += __shfl_xor(rs[r], m, 64);
  if (l15 == 0) {
#pragma unroll
    for (int r = 0; r < 4; ++r) sRS[kh][qg * 16 + lg * 4 + r] = rs[r];
  }
  __syncthreads();
  if (tid < 64) sInv[tid] = 1.f / (sRS[0][tid] + sRS[1][tid]);
  __syncthreads();
  float inv4[4];
#pragma unroll
  for (int r = 0; r < 4; ++r) inv4[r] = sInv[qg * 16 + lg * 4 + r];

  // ---------------- Phase B: P write + PV ----------------
  f32x4 accY[8];
#pragma unroll
  for (int t = 0; t < 8; ++t) accY[t] = (f32x4){0, 0, 0, 0};
  float* PnW = P + ((size_t)n * HW + q0 + qg * 16) * HW;

  for (int k0 = kh * 2048, it = 0; it < 32; ++it, k0 += 64) {
    __syncthreads();
#pragma unroll
    for (int rep = 0; rep < 4; ++rep) {
      int row = (u >> 4) + rep * 16, seg = u & 15;
      *reinterpret_cast<bf16x8*>(&sPhi[kh][row][seg * 8]) =
          *reinterpret_cast<const bf16x8*>(&phN[(size_t)(k0 + row) * IC + seg * 8]);
    }
#pragma unroll
    for (int rep = 0; rep < 4; ++rep) {
      int row = (u >> 3) + rep * 32, seg = u & 7;
      *reinterpret_cast<bf16x8*>(&sG[kh][row][seg * 8]) =
          *reinterpret_cast<const bf16x8*>(&gN[(size_t)row * HW + k0 + seg * 8]);
    }
    __syncthreads();
    f32x4 cc[4] = {{0, 0, 0, 0}, {0, 0, 0, 0}, {0, 0, 0, 0}, {0, 0, 0, 0}};
#pragma unroll
    for (int kt = 0; kt < 4; ++kt)
#pragma unroll
      for (int cj = 0; cj < 4; ++cj) {
        bf16x8 b = *reinterpret_cast<const bf16x8*>(&sPhi[kh][kt * 16 + l15][cj * 32 + lg * 8]);
        cc[kt] = MFMA16(aQ[cj], b, cc[kt]);
      }
#pragma unroll
    for (int kt = 0; kt < 4; ++kt)
#pragma unroll
      for (int r = 0; r < 4; ++r) {
        float p = __expf(cc[kt][r] * scale) * inv4[r];
        PnW[(size_t)(lg * 4 + r) * HW + (k0 + kt * 16 + l15)] = p;
        sPb[wv][lg * 4 + r][kt * 16 + l15] = (__bf16)p;
      }
    __syncthreads();
    bf16x8 aP0 = *reinterpret_cast<const bf16x8*>(&sPb[wv][l15][lg * 8]);
    bf16x8 aP1 = *reinterpret_cast<const bf16x8*>(&sPb[wv][l15][lg * 8 + 32]);
#pragma unroll
    for (int t = 0; t < 8; ++t) {
      bf16x8 b0 = *reinterpret_cast<const bf16x8*>(&sG[kh][t * 16 + l15][lg * 8]);
      bf16x8 b1 = *reinterpret_cast<const bf16x8*>(&sG[kh][t * 16 + l15][lg * 8 + 32]);
      accY[t] = MFMA16(aP0, b0, accY[t]);
      accY[t] = MFMA16(aP1, b1, accY[t]);
    }
  }

  // combine k-halves via LDS, write yT
  __syncthreads();
  if (kh == 0) {
#pragma unroll
    for (int t = 0; t < 8; ++t)
#pragma unroll
      for (int r = 0; r < 4; ++r)
        sY[qg * 16 + lg * 4 + r][t * 16 + l15] = accY[t][r];
  }
  __syncthreads();
  if (kh == 1) {
    float* yRow = yT + ((size_t)n * HW + q0 + qg * 16) * IC;
#pragma unroll
    for (int t = 0; t < 8; ++t)
#pragma unroll
      for (int r = 0; r < 4; ++r)
        yRow[(size_t)(lg * 4 + r) * IC + t * 16 + l15] =
            accY[t][r] + sY[qg * 16 + lg * 4 + r][t * 16 + l15];
  }
}

// ---------------------------------------------------------------------------
// out conv: y2[n][o][p] = sum_ic out_w[o][ic]*yT[n][p][ic] + b[o]
__global__ __launch_bounds__(256) void k_outconv(const float* __restrict__ yT,
                                                 const float* __restrict__ w,
                                                 const float* __restrict__ bias,
                                                 float* __restrict__ y2) {
  const int n = blockIdx.y;
  const int p0 = (blockIdx.x & 63) * 64;
  const int o0 = (blockIdx.x >> 6) * 64;
  __shared__ float sY[64][132];
  __shared__ float sW[64][132];
  const int tid = threadIdx.x;
  const int tx = tid & 15, ty = tid >> 4;
  {
    const float* src = yT + ((size_t)n * HW + p0) * IC;
    const float* srcw = w + (size_t)o0 * IC;
#pragma unroll
    for (int i = 0; i < 8; ++i) {
      int e4 = tid + 256 * i;
      int row = e4 >> 5, c4 = e4 & 31;
      st4(&sY[row][c4 * 4], ld4(&src[(size_t)row * IC + c4 * 4]));
      st4(&sW[row][c4 * 4], ld4(&srcw[(size_t)row * IC + c4 * 4]));
    }
  }
  __syncthreads();
  float acc[4][4] = {};
#pragma unroll 4
  for (int kk = 0; kk < 32; ++kk) {
    float4 a0 = ld4(&sY[tx + 0][kk * 4]);
    float4 a1 = ld4(&sY[tx + 16][kk * 4]);
    float4 a2 = ld4(&sY[tx + 32][kk * 4]);
    float4 a3 = ld4(&sY[tx + 48][kk * 4]);
    float4 b0 = ld4(&sW[ty * 4 + 0][kk * 4]);
    float4 b1 = ld4(&sW[ty * 4 + 1][kk * 4]);
    float4 b2 = ld4(&sW[ty * 4 + 2][kk * 4]);
    float4 b3 = ld4(&sW[ty * 4 + 3][kk * 4]);
    FMA4(acc[0][0], a0, b0) FMA4(acc[0][1], a0, b1) FMA4(acc[0][2], a0, b2) FMA4(acc[0][3], a0, b3)
    FMA4(acc[1][0], a1, b0) FMA4(acc[1][1], a1, b1) FMA4(acc[1][2], a1, b2) FMA4(acc[1][3], a1, b3)
    FMA4(acc[2][0], a2, b0) FMA4(acc[2][1], a2, b1) FMA4(acc[2][2], a2, b2) FMA4(acc[2][3], a2, b3)
    FMA4(acc[3][0], a3, b0) FMA4(acc[3][1], a3, b1) FMA4(acc[3][2], a3, b2) FMA4(acc[3][3], a3, b3)
  }
#pragma unroll
  for (int j = 0; j < 4; ++j) {
    float bb = bias[o0 + ty * 4 + j];
    float* dst = &y2[((size_t)n * CCH + o0 + ty * 4 + j) * HW + p0];
#pragma unroll
    for (int i = 0; i < 4; ++i) dst[tx + 16 * i] = acc[i][j] + bb;
  }
}

// ---------------------------------------------------------------------------
__global__ __launch_bounds__(256) void k_c1(const float* __restrict__ x,
                                            const float* __restrict__ y2,
                                            const float* __restrict__ w,
                                            const float* __restrict__ bias,
                                            float* __restrict__ coef1) {
  const int n = blockIdx.y;
  const int p0 = (blockIdx.x & 63) * 64;
  const int o0 = (blockIdx.x >> 6) * 64;
  __shared__ float sIn[16][68];
  __shared__ float sW[16][68];
  const int tid = threadIdx.x;
  const int tx = tid & 15, ty = tid >> 4;
  float acc[4][4] = {};
  for (int c0 = 0; c0 < 512; c0 += 16) {
    __syncthreads();
    const float* src = (c0 < 256)
                           ? (x + (size_t)n * CCH * HW + (size_t)c0 * HW)
                           : (y2 + (size_t)n * CCH * HW + (size_t)(c0 - 256) * HW);
    {
      int cc = tid >> 4, p4 = tid & 15;
      st4(&sIn[cc][p4 * 4], ld4(&src[(size_t)cc * HW + p0 + p4 * 4]));
    }
    {
      int o = tid >> 2, c4 = tid & 3;
      float4 wv = ld4(&w[(size_t)(o0 + o) * 512 + c0 + c4 * 4]);
      sW[c4 * 4 + 0][o] = wv.x;
      sW[c4 * 4 + 1][o] = wv.y;
      sW[c4 * 4 + 2][o] = wv.z;
      sW[c4 * 4 + 3][o] = wv.w;
    }
    __syncthreads();
#pragma unroll
    for (int kk = 0; kk < 16; ++kk) {
      float4 bv = ld4(&sIn[kk][tx * 4]);
      float4 av = ld4(&sW[kk][ty * 4]);
      float bb[4] = {bv.x, bv.y, bv.z, bv.w};
      float aa[4] = {av.x, av.y, av.z, av.w};
#pragma unroll
      for (int i = 0; i < 4; ++i)
#pragma unroll
        for (int j = 0; j < 4; ++j) acc[i][j] = fmaf(bb[i], aa[j], acc[i][j]);
    }
  }
#pragma unroll
  for (int j = 0; j < 4; ++j) {
    float bb = bias[o0 + ty * 4 + j];
    float4 v = make_float4(fmaxf(acc[0][j] + bb, 0.f), fmaxf(acc[1][j] + bb, 0.f),
                           fmaxf(acc[2][j] + bb, 0.f), fmaxf(acc[3][j] + bb, 0.f));
    st4(&coef1[((size_t)n * CCH + o0 + ty * 4 + j) * HW + p0 + tx * 4], v);
  }
}

// ---------------------------------------------------------------------------
__global__ __launch_bounds__(256) void k_c2p(const float* __restrict__ coef1,
                                             const float* __restrict__ w,
                                             float* __restrict__ part) {
  const int n = blockIdx.y;
  const int kc = blockIdx.z;
  const int p = blockIdx.x * 256 + threadIdx.x;
  const int px = p & 63, py = p >> 6;
  float acc[16];
#pragma unroll
  for (int o = 0; o < 16; ++o) acc[o] = 0.f;
  const float* base = coef1 + (size_t)n * CCH * HW + (size_t)kc * 64 * HW;
  for (int c = 0; c < 64; ++c) {
    const float* img = base + (size_t)c * HW;
    float v[9];
#pragma unroll
    for (int dy = -1; dy <= 1; ++dy)
#pragma unroll
      for (int dx = -1; dx <= 1; ++dx) {
        int yy = py + dy, xx = px + dx;
        bool ok = ((unsigned)yy < 64u) && ((unsigned)xx < 64u);
        v[(dy + 1) * 3 + dx + 1] = ok ? img[yy * 64 + xx] : 0.f;
      }
    const int cg = kc * 64 + c;
#pragma unroll
    for (int o = 0; o < 16; ++o) {
      const float* wp = w + ((size_t)o * CCH + cg) * 9;
      float a = acc[o];
      a = fmaf(wp[0], v[0], a); a = fmaf(wp[1], v[1], a); a = fmaf(wp[2], v[2], a);
      a = fmaf(wp[3], v[3], a); a = fmaf(wp[4], v[4], a); a = fmaf(wp[5], v[5], a);
      a = fmaf(wp[6], v[6], a); a = fmaf(wp[7], v[7], a); a = fmaf(wp[8], v[8], a);
      acc[o] = a;
    }
  }
  float* dst = part + (((size_t)kc * 4 + n) * 16) * HW + p;
#pragma unroll
  for (int o = 0; o < 16; ++o) dst[(size_t)o * HW] = acc[o];
}

__global__ __launch_bounds__(256) void k_c2r(const float* __restrict__ part,
                                             const float* __restrict__ bias,
                                             float* __restrict__ c2o) {
  const int n = blockIdx.y;
  const int p = blockIdx.x * 256 + threadIdx.x;
#pragma unroll
  for (int o = 0; o < 16; ++o) {
    float s = bias[o];
#pragma unroll
    for (int kc = 0; kc < 4; ++kc)
      s += part[(((size_t)kc * 4 + n) * 16 + o) * HW + p];
    c2o[((size_t)n * 16 + o) * HW + p] = fmaxf(s, 0.f);
  }
}

// ---------------------------------------------------------------------------
__global__ __launch_bounds__(256) void k_c3(const float* __restrict__ c2o,
                                            const float* __restrict__ w,
                                            const float* __restrict__ bias,
                                            float* __restrict__ c3o) {
  const int n = blockIdx.y;
  const int p = blockIdx.x * 256 + threadIdx.x;
  const int px = p & 63, py = p >> 6;
  float acc[3] = {bias[0], bias[1], bias[2]};
  for (int c = 0; c < 16; ++c) {
    const float* img = c2o + ((size_t)n * 16 + c) * HW;
    float v[9];
#pragma unroll
    for (int dy = -1; dy <= 1; ++dy)
#pragma unroll
      for (int dx = -1; dx <= 1; ++dx) {
        int yy = py + dy, xx = px + dx;
        bool ok = ((unsigned)yy < 64u) && ((unsigned)xx < 64u);
        v[(dy + 1) * 3 + dx + 1] = ok ? img[yy * 64 + xx] : 0.f;
      }
#pragma unroll
    for (int o = 0; o < 3; ++o) {
      const float* wp = w + ((size_t)o * 16 + c) * 9;
      float a = acc[o];
      a = fmaf(wp[0], v[0], a); a = fmaf(wp[1], v[1], a); a = fmaf(wp[2], v[2], a);
      a = fmaf(wp[3], v[3], a); a = fmaf(wp[4], v[4], a); a = fmaf(wp[5], v[5], a);
      a = fmaf(wp[6], v[6], a); a = fmaf(wp[7], v[7], a); a = fmaf(wp[8], v[8], a);
      acc[o] = a;
    }
  }
#pragma unroll
  for (int o = 0; o < 3; ++o)
    c3o[((size_t)n * 3 + o) * HW + p] = fmaxf(acc[o], 0.f);
}

// ---------------------------------------------------------------------------
__global__ __launch_bounds__(256) void k_c4f(const float* __restrict__ c3o,
                                             const float* __restrict__ w4,
                                             const float* __restrict__ b4,
                                             const float* __restrict__ x,
                                             const float* __restrict__ y2,
                                             float* __restrict__ out0) {
  const int n = blockIdx.y;
  const int cc = blockIdx.z;
  const int p = blockIdx.x * 256 + threadIdx.x;
  const int px = p & 63, py = p >> 6;
  float coef = b4[0];
#pragma unroll
  for (int c = 0; c < 3; ++c) {
    const float* img = c3o + ((size_t)n * 3 + c) * HW;
#pragma unroll
    for (int dy = -1; dy <= 1; ++dy)
#pragma unroll
      for (int dx = -1; dx <= 1; ++dx) {
        int yy = py + dy, xx = px + dx;
        bool ok = ((unsigned)yy < 64u) && ((unsigned)xx < 64u);
        float v = ok ? img[yy * 64 + xx] : 0.f;
        coef = fmaf(w4[c * 9 + (dy + 1) * 3 + dx + 1], v, coef);
      }
  }
  const size_t base = ((size_t)n * CCH + cc * 64) * HW + p;
#pragma unroll 8
  for (int c = 0; c < 64; ++c) {
    size_t a = base + (size_t)c * HW;
    out0[a] = x[a] + coef * y2[a];
  }
}

// ---------------------------------------------------------------------------
extern "C" void kernel_launch(void* const* d_in, const int* in_sizes, int n_in,
                              void* d_out, int out_size, void* d_ws, size_t ws_size,
                              hipStream_t stream) {
  (void)in_sizes; (void)n_in; (void)out_size; (void)ws_size;
  const float* x     = (const float*)d_in[0];
  const float* x_ref = (const float*)d_in[1];
  const float* g_w   = (const float*)d_in[2];
  const float* g_b   = (const float*)d_in[3];
  const float* th_w  = (const float*)d_in[4];
  const float* th_b  = (const float*)d_in[5];
  const float* ph_w  = (const float*)d_in[6];
  const float* ph_b  = (const float*)d_in[7];
  const float* out_w = (const float*)d_in[8];
  const float* out_b = (const float*)d_in[9];
  const float* c1_w  = (const float*)d_in[10];
  const float* c1_b  = (const float*)d_in[11];
  const float* c2_w  = (const float*)d_in[12];
  const float* c2_b  = (const float*)d_in[13];
  const float* c3_w  = (const float*)d_in[14];
  const float* c3_b  = (const float*)d_in[15];
  const float* c4_w  = (const float*)d_in[16];
  const float* c4_b  = (const float*)d_in[17];

  float* ws = (float*)d_ws;
  // float-offset region plan:
  //   [0 .. 1M)      thB  (bf16)      } dead after k_attn
  //   [1M .. 2M)     phB  (bf16)      }   -> reused as coef1 [0 .. 4M)
  //   [2M .. 3M)     gB   (bf16)      }
  //   [3M .. 5M)     yT   (fp32)      } dead after k_outconv
  //   [5M .. 9M)     y2   (fp32, lives to end)
  //   [9M .. 10M)    c2p
  //   [10M .. 10.25M) c2o ; then c3o
  __bf16* thB = (__bf16*)(ws + 0);
  __bf16* phB = (__bf16*)(ws + 1048576);
  __bf16* gBf = (__bf16*)(ws + 2097152);
  float* yT    = ws + 3145728;
  float* y2    = ws + 5242880;
  float* coef1 = ws + 0;
  float* c2p   = ws + 9437184;
  float* c2o   = ws + 10485760;
  float* c3o   = ws + 10747904;

  float* out0 = (float*)d_out;
  float* P    = out0 + 4194304;

  dim3 blk(256);
  k_projA<<<dim3(64, 4), blk, 0, stream>>>(x, th_w, th_b, thB);
  k_projA<<<dim3(64, 4), blk, 0, stream>>>(x_ref, ph_w, ph_b, phB);
  k_projG<<<dim3(64, 4), blk, 0, stream>>>(x_ref, g_w, g_b, gBf);
  k_attn<<<dim3(64, 4), dim3(512), 0, stream>>>(thB, phB, gBf, P, yT);
  k_outconv<<<dim3(256, 4), blk, 0, stream>>>(yT, out_w, out_b, y2);
  k_c1<<<dim3(256, 4), blk, 0, stream>>>(x, y2, c1_w, c1_b, coef1);
  k_c2p<<<dim3(16, 4, 4), blk, 0, stream>>>(coef1, c2_w, c2p);
  k_c2r<<<dim3(16, 4), blk, 0, stream>>>(c2p, c2_b, c2o);
  k_c3<<<dim3(16, 4), blk, 0, stream>>>(c2o, c3_w, c3_b, c3o);
  k_c4f<<<dim3(16, 4, 4), blk, 0, stream>>>(c3o, c4_w, c4_b, x, y2, out0);
}

// Round 3
// 411.923 us; speedup vs baseline: 2.4466x; 1.0186x over previous
//
#include <hip/hip_runtime.h>

#define HW 4096
#define CCH 256
#define IC 128

typedef __bf16 bf16x8 __attribute__((ext_vector_type(8)));
typedef float f32x4 __attribute__((ext_vector_type(4)));

#define MFMA16(a, b, c) __builtin_amdgcn_mfma_f32_16x16x32_bf16(a, b, c, 0, 0, 0)

static __device__ __forceinline__ float4 ld4(const float* p) {
  return *reinterpret_cast<const float4*>(p);
}
static __device__ __forceinline__ void st4(float* p, float4 v) {
  *reinterpret_cast<float4*>(p) = v;
}
static __device__ __forceinline__ unsigned int pack_bf16(float a, float b) {
  union { __bf16 h; unsigned short u; } ua, ub;
  ua.h = (__bf16)a; ub.h = (__bf16)b;
  return ((unsigned int)ub.u << 16) | (unsigned int)ua.u;
}
static __device__ __forceinline__ bf16x8 ldb8(const __bf16* p) {
  return *reinterpret_cast<const bf16x8*>(p);
}

// ---------------------------------------------------------------------------
// theta projection (pixel-major bf16) + xB emission (x transposed, bf16 [px][256])
__global__ __launch_bounds__(256) void k_projT(const float* __restrict__ in,
                                               const float* __restrict__ w,
                                               const float* __restrict__ bias,
                                               __bf16* __restrict__ out,
                                               __bf16* __restrict__ xB) {
  const int n = blockIdx.y;
  const int p0 = blockIdx.x * 64;
  const float* inN = in + (size_t)n * CCH * HW;
  __shared__ float sIn[16][68];
  __shared__ float sW[16][132];
  const int tid = threadIdx.x;
  const int tp = tid & 15, to = tid >> 4;
  const int px = tid & 63, cp = tid >> 6;
  float acc[4][8];
#pragma unroll
  for (int i = 0; i < 4; ++i)
#pragma unroll
    for (int j = 0; j < 8; ++j) acc[i][j] = 0.f;

  for (int c0 = 0; c0 < CCH; c0 += 16) {
    __syncthreads();
    {
      int cc = tid >> 4, p4 = tid & 15;
      st4(&sIn[cc][p4 * 4], ld4(&inN[(size_t)(c0 + cc) * HW + p0 + p4 * 4]));
    }
#pragma unroll
    for (int i = 0; i < 2; ++i) {
      int e4 = tid + 256 * i;
      int o = e4 >> 2, c4 = e4 & 3;
      float4 wv = ld4(&w[(size_t)o * CCH + c0 + c4 * 4]);
      sW[c4 * 4 + 0][o] = wv.x;
      sW[c4 * 4 + 1][o] = wv.y;
      sW[c4 * 4 + 2][o] = wv.z;
      sW[c4 * 4 + 3][o] = wv.w;
    }
    __syncthreads();
    // xB transpose emission (bf16 pairs)
    {
      unsigned int* xr = (unsigned int*)(xB + ((size_t)n * HW + p0 + px) * 256 + c0);
#pragma unroll
      for (int i = 0; i < 2; ++i) {
        int ch2 = 2 * (cp + 4 * i);
        xr[cp + 4 * i] = pack_bf16(sIn[ch2][px], sIn[ch2 + 1][px]);
      }
    }
#pragma unroll
    for (int kk = 0; kk < 16; ++kk) {
      float4 bv = ld4(&sIn[kk][tp * 4]);
      float4 a0 = ld4(&sW[kk][to * 8]);
      float4 a1 = ld4(&sW[kk][to * 8 + 4]);
      float bb[4] = {bv.x, bv.y, bv.z, bv.w};
      float aa[8] = {a0.x, a0.y, a0.z, a0.w, a1.x, a1.y, a1.z, a1.w};
#pragma unroll
      for (int i = 0; i < 4; ++i)
#pragma unroll
        for (int j = 0; j < 8; ++j) acc[i][j] = fmaf(bb[i], aa[j], acc[i][j]);
    }
  }
  float bs[8];
#pragma unroll
  for (int j = 0; j < 8; ++j) bs[j] = bias[to * 8 + j];
  __bf16* dst = out + ((size_t)n * HW + p0) * IC;
#pragma unroll
  for (int i = 0; i < 4; ++i) {
    bf16x8 v;
#pragma unroll
    for (int j = 0; j < 8; ++j) v[j] = (__bf16)(acc[i][j] + bs[j]);
    *reinterpret_cast<bf16x8*>(&dst[(size_t)(tp * 4 + i) * IC + to * 8]) = v;
  }
}

// ---------------------------------------------------------------------------
// phi (pixel-major) + g (channel-major) projections, one pass over x_ref
__global__ __launch_bounds__(256) void k_projPG(const float* __restrict__ in,
                                                const float* __restrict__ wPhi,
                                                const float* __restrict__ wG,
                                                const float* __restrict__ bPhi,
                                                const float* __restrict__ bG,
                                                __bf16* __restrict__ phB,
                                                __bf16* __restrict__ gB) {
  const int n = blockIdx.y;
  const int p0 = blockIdx.x * 64;
  const float* inN = in + (size_t)n * CCH * HW;
  __shared__ float sIn[16][68];
  __shared__ float sW[16][264];
  __shared__ __attribute__((aligned(16))) __bf16 sT[128][72];
  const int tid = threadIdx.x;
  const int tp = tid & 15, to = tid >> 4;
  float acc[4][16];
#pragma unroll
  for (int i = 0; i < 4; ++i)
#pragma unroll
    for (int j = 0; j < 16; ++j) acc[i][j] = 0.f;

  for (int c0 = 0; c0 < CCH; c0 += 16) {
    __syncthreads();
    {
      int cc = tid >> 4, p4 = tid & 15;
      st4(&sIn[cc][p4 * 4], ld4(&inN[(size_t)(c0 + cc) * HW + p0 + p4 * 4]));
    }
#pragma unroll
    for (int i = 0; i < 4; ++i) {
      int e4 = tid + 256 * i;
      int o = e4 >> 2, c4 = e4 & 3;
      const float* wsrc = (o < 128) ? &wPhi[(size_t)o * CCH + c0 + c4 * 4]
                                    : &wG[(size_t)(o - 128) * CCH + c0 + c4 * 4];
      float4 wv = ld4(wsrc);
      sW[c4 * 4 + 0][o] = wv.x;
      sW[c4 * 4 + 1][o] = wv.y;
      sW[c4 * 4 + 2][o] = wv.z;
      sW[c4 * 4 + 3][o] = wv.w;
    }
    __syncthreads();
#pragma unroll
    for (int kk = 0; kk < 16; ++kk) {
      float4 bv = ld4(&sIn[kk][tp * 4]);
      float bb[4] = {bv.x, bv.y, bv.z, bv.w};
      float aa[16];
      float4 a0 = ld4(&sW[kk][to * 16 + 0]);
      float4 a1 = ld4(&sW[kk][to * 16 + 4]);
      float4 a2 = ld4(&sW[kk][to * 16 + 8]);
      float4 a3 = ld4(&sW[kk][to * 16 + 12]);
      aa[0]=a0.x; aa[1]=a0.y; aa[2]=a0.z; aa[3]=a0.w;
      aa[4]=a1.x; aa[5]=a1.y; aa[6]=a1.z; aa[7]=a1.w;
      aa[8]=a2.x; aa[9]=a2.y; aa[10]=a2.z; aa[11]=a2.w;
      aa[12]=a3.x; aa[13]=a3.y; aa[14]=a3.z; aa[15]=a3.w;
#pragma unroll
      for (int i = 0; i < 4; ++i)
#pragma unroll
        for (int j = 0; j < 16; ++j) acc[i][j] = fmaf(bb[i], aa[j], acc[i][j]);
    }
  }
  float bs[16];
#pragma unroll
  for (int j = 0; j < 16; ++j) {
    int o = to * 16 + j;
    bs[j] = (o < 128) ? bPhi[o] : bG[o - 128];
  }
  if (to < 8) {  // phi: pixel-major
    __bf16* dst = phB + ((size_t)n * HW + p0) * IC;
#pragma unroll
    for (int i = 0; i < 4; ++i) {
      bf16x8 v0, v1;
#pragma unroll
      for (int j = 0; j < 8; ++j) {
        v0[j] = (__bf16)(acc[i][j] + bs[j]);
        v1[j] = (__bf16)(acc[i][8 + j] + bs[8 + j]);
      }
      *reinterpret_cast<bf16x8*>(&dst[(size_t)(tp * 4 + i) * IC + to * 16]) = v0;
      *reinterpret_cast<bf16x8*>(&dst[(size_t)(tp * 4 + i) * IC + to * 16 + 8]) = v1;
    }
  }
  __syncthreads();
  if (to >= 8) {  // g: transpose to channel-major via LDS
#pragma unroll
    for (int i = 0; i < 4; ++i)
#pragma unroll
      for (int j = 0; j < 16; ++j)
        sT[(to - 8) * 16 + j][tp * 4 + i] = (__bf16)(acc[i][j] + bs[j]);
  }
  __syncthreads();
  const int row = tid >> 1, half = tid & 1;
  __bf16* dst = gB + (size_t)n * IC * HW + (size_t)row * HW + p0 + half * 32;
#pragma unroll
  for (int m = 0; m < 4; ++m)
    *reinterpret_cast<bf16x8*>(&dst[m * 8]) =
        *reinterpret_cast<const bf16x8*>(&sT[row][half * 32 + m * 8]);
}

// ---------------------------------------------------------------------------
// prep: W2 = c1y@out_w (bf16), bias2 = c1_b + c1y@out_b, cast c1x & out_w to bf16
__global__ __launch_bounds__(256) void k_prep(const float* __restrict__ c1_w,
                                              const float* __restrict__ c1_b,
                                              const float* __restrict__ out_w,
                                              const float* __restrict__ out_b,
                                              __bf16* __restrict__ c1xB,
                                              __bf16* __restrict__ W2B,
                                              __bf16* __restrict__ outwB,
                                              float* __restrict__ bias2) {
  const int bx = blockIdx.x, tid = threadIdx.x;
  if (bx < 256) {
    const int o = bx;
    c1xB[(size_t)o * 256 + tid] = (__bf16)c1_w[(size_t)o * 512 + tid];
    if (tid < 128) {
      float s = 0.f;
      for (int c = 0; c < 256; ++c)
        s = fmaf(c1_w[(size_t)o * 512 + 256 + c], out_w[(size_t)c * 128 + tid], s);
      W2B[(size_t)o * 128 + tid] = (__bf16)s;
    } else if (tid == 128) {
      float s = 0.f;
      for (int c = 0; c < 256; ++c)
        s = fmaf(c1_w[(size_t)o * 512 + 256 + c], out_b[c], s);
      bias2[o] = c1_b[o] + s;
    }
  } else {
    const int o = bx - 256;
    if (tid < 128) outwB[(size_t)o * 128 + tid] = (__bf16)out_w[(size_t)o * 128 + tid];
  }
}

// ---------------------------------------------------------------------------
// Fused attention: P (fp32 out) + yTB (bf16 [px][128])
__global__ __launch_bounds__(512) void k_attn(const __bf16* __restrict__ thB,
                                              const __bf16* __restrict__ phB,
                                              const __bf16* __restrict__ gB,
                                              float* __restrict__ P,
                                              __bf16* __restrict__ yTB) {
  const int n = blockIdx.y;
  const int q0 = blockIdx.x * 64;
  const int tid = threadIdx.x;
  const int wv = tid >> 6;
  const int lane = tid & 63;
  const int qg = wv & 3;
  const int kh = wv >> 2;
  const int l15 = lane & 15;
  const int lg = lane >> 4;

  __shared__ __attribute__((aligned(16))) __bf16 sPhi[2][64][136];
  __shared__ __attribute__((aligned(16))) __bf16 sG[2][128][72];
  __shared__ __attribute__((aligned(16))) __bf16 sPb[8][16][72];
  __shared__ float sY[64][132];
  __shared__ float sRS[2][64];
  __shared__ float sInv[64];

  const __bf16* phN = phB + (size_t)n * HW * IC;
  const __bf16* gN = gB + (size_t)n * IC * HW;
  const float scale = 0.08838834764831845f;  // 1/sqrt(128)

  const __bf16* thRow = thB + ((size_t)n * HW + q0 + qg * 16 + l15) * IC + lg * 8;
  bf16x8 aQ[4];
#pragma unroll
  for (int cj = 0; cj < 4; ++cj)
    aQ[cj] = ldb8(thRow + 32 * cj);

  const int u = tid & 255;

  // ---------------- Phase A: rowsums ----------------
  float rs[4] = {0.f, 0.f, 0.f, 0.f};
  for (int k0 = kh * 2048, it = 0; it < 32; ++it, k0 += 64) {
    __syncthreads();
#pragma unroll
    for (int rep = 0; rep < 4; ++rep) {
      int row = (u >> 4) + rep * 16, seg = u & 15;
      *reinterpret_cast<bf16x8*>(&sPhi[kh][row][seg * 8]) =
          ldb8(&phN[(size_t)(k0 + row) * IC + seg * 8]);
    }
    __syncthreads();
    f32x4 cc[4] = {{0, 0, 0, 0}, {0, 0, 0, 0}, {0, 0, 0, 0}, {0, 0, 0, 0}};
#pragma unroll
    for (int kt = 0; kt < 4; ++kt)
#pragma unroll
      for (int cj = 0; cj < 4; ++cj) {
        bf16x8 b = ldb8(&sPhi[kh][kt * 16 + l15][cj * 32 + lg * 8]);
        cc[kt] = MFMA16(aQ[cj], b, cc[kt]);
      }
#pragma unroll
    for (int kt = 0; kt < 4; ++kt)
#pragma unroll
      for (int r = 0; r < 4; ++r) rs[r] += __expf(cc[kt][r] * scale);
  }
#pragma unroll
  for (int m = 1; m < 16; m <<= 1)
#pragma unroll
    for (int r = 0; r < 4; ++r) rs[r] += __shfl_xor(rs[r], m, 64);
  if (l15 == 0) {
#pragma unroll
    for (int r = 0; r < 4; ++r) sRS[kh][qg * 16 + lg * 4 + r] = rs[r];
  }
  __syncthreads();
  if (tid < 64) sInv[tid] = 1.f / (sRS[0][tid] + sRS[1][tid]);
  __syncthreads();
  float inv4[4];
#pragma unroll
  for (int r = 0; r < 4; ++r) inv4[r] = sInv[qg * 16 + lg * 4 + r];

  // ---------------- Phase B: P write + PV ----------------
  f32x4 accY[8];
#pragma unroll
  for (int t = 0; t < 8; ++t) accY[t] = (f32x4){0, 0, 0, 0};
  float* PnW = P + ((size_t)n * HW + q0 + qg * 16) * HW;

  for (int k0 = kh * 2048, it = 0; it < 32; ++it, k0 += 64) {
    __syncthreads();
#pragma unroll
    for (int rep = 0; rep < 4; ++rep) {
      int row = (u >> 4) + rep * 16, seg = u & 15;
      *reinterpret_cast<bf16x8*>(&sPhi[kh][row][seg * 8]) =
          ldb8(&phN[(size_t)(k0 + row) * IC + seg * 8]);
    }
#pragma unroll
    for (int rep = 0; rep < 4; ++rep) {
      int row = (u >> 3) + rep * 32, seg = u & 7;
      *reinterpret_cast<bf16x8*>(&sG[kh][row][seg * 8]) =
          ldb8(&gN[(size_t)row * HW + k0 + seg * 8]);
    }
    __syncthreads();
    f32x4 cc[4] = {{0, 0, 0, 0}, {0, 0, 0, 0}, {0, 0, 0, 0}, {0, 0, 0, 0}};
#pragma unroll
    for (int kt = 0; kt < 4; ++kt)
#pragma unroll
      for (int cj = 0; cj < 4; ++cj) {
        bf16x8 b = ldb8(&sPhi[kh][kt * 16 + l15][cj * 32 + lg * 8]);
        cc[kt] = MFMA16(aQ[cj], b, cc[kt]);
      }
#pragma unroll
    for (int kt = 0; kt < 4; ++kt)
#pragma unroll
      for (int r = 0; r < 4; ++r) {
        float p = __expf(cc[kt][r] * scale) * inv4[r];
        PnW[(size_t)(lg * 4 + r) * HW + (k0 + kt * 16 + l15)] = p;
        sPb[wv][lg * 4 + r][kt * 16 + l15] = (__bf16)p;
      }
    __syncthreads();
    bf16x8 aP0 = ldb8(&sPb[wv][l15][lg * 8]);
    bf16x8 aP1 = ldb8(&sPb[wv][l15][lg * 8 + 32]);
#pragma unroll
    for (int t = 0; t < 8; ++t) {
      bf16x8 b0 = ldb8(&sG[kh][t * 16 + l15][lg * 8]);
      bf16x8 b1 = ldb8(&sG[kh][t * 16 + l15][lg * 8 + 32]);
      accY[t] = MFMA16(aP0, b0, accY[t]);
      accY[t] = MFMA16(aP1, b1, accY[t]);
    }
  }

  __syncthreads();
  if (kh == 0) {
#pragma unroll
    for (int t = 0; t < 8; ++t)
#pragma unroll
      for (int r = 0; r < 4; ++r)
        sY[qg * 16 + lg * 4 + r][t * 16 + l15] = accY[t][r];
  }
  __syncthreads();
  if (kh == 1) {
    __bf16* yRow = yTB + ((size_t)n * HW + q0 + qg * 16) * IC;
#pragma unroll
    for (int t = 0; t < 8; ++t)
#pragma unroll
      for (int r = 0; r < 4; ++r)
        yRow[(size_t)(lg * 4 + r) * IC + t * 16 + l15] =
            (__bf16)(accY[t][r] + sY[qg * 16 + lg * 4 + r][t * 16 + l15]);
  }
}

// ---------------------------------------------------------------------------
// c1 via MFMA (LDS-free): coef1 = relu(c1xB@xB + W2B@yTB + bias2), bf16 out
__global__ __launch_bounds__(256) void k_c1m(const __bf16* __restrict__ xB,
                                             const __bf16* __restrict__ yTB,
                                             const __bf16* __restrict__ c1xB,
                                             const __bf16* __restrict__ W2B,
                                             const float* __restrict__ bias2,
                                             __bf16* __restrict__ coef1) {
  const int n = blockIdx.y;
  const int px0 = blockIdx.x * 64;
  const int tid = threadIdx.x;
  const int w = tid >> 6, lane = tid & 63;
  const int l15 = lane & 15, lg = lane >> 4;
  const int o0 = w * 64;
  f32x4 acc[4][4];
#pragma unroll
  for (int i = 0; i < 4; ++i)
#pragma unroll
    for (int j = 0; j < 4; ++j) acc[i][j] = (f32x4){0, 0, 0, 0};

  const __bf16* xRow = xB + ((size_t)n * HW + px0) * 256;
  const __bf16* yRow = yTB + ((size_t)n * HW + px0) * 128;

#pragma unroll
  for (int s = 0; s < 8; ++s) {
    bf16x8 a[4], b[4];
#pragma unroll
    for (int t = 0; t < 4; ++t) {
      a[t] = ldb8(&c1xB[(size_t)(o0 + t * 16 + l15) * 256 + s * 32 + lg * 8]);
      b[t] = ldb8(&xRow[(size_t)(t * 16 + l15) * 256 + s * 32 + lg * 8]);
    }
#pragma unroll
    for (int i = 0; i < 4; ++i)
#pragma unroll
      for (int j = 0; j < 4; ++j) acc[i][j] = MFMA16(a[i], b[j], acc[i][j]);
  }
#pragma unroll
  for (int s = 0; s < 4; ++s) {
    bf16x8 a[4], b[4];
#pragma unroll
    for (int t = 0; t < 4; ++t) {
      a[t] = ldb8(&W2B[(size_t)(o0 + t * 16 + l15) * 128 + s * 32 + lg * 8]);
      b[t] = ldb8(&yRow[(size_t)(t * 16 + l15) * 128 + s * 32 + lg * 8]);
    }
#pragma unroll
    for (int i = 0; i < 4; ++i)
#pragma unroll
      for (int j = 0; j < 4; ++j) acc[i][j] = MFMA16(a[i], b[j], acc[i][j]);
  }
#pragma unroll
  for (int i = 0; i < 4; ++i)
#pragma unroll
    for (int r = 0; r < 4; ++r) {
      int o = o0 + i * 16 + lg * 4 + r;
      float bb = bias2[o];
      __bf16* dst = coef1 + ((size_t)n * CCH + o) * HW + px0;
#pragma unroll
      for (int j = 0; j < 4; ++j)
        dst[j * 16 + l15] = (__bf16)fmaxf(acc[i][j][r] + bb, 0.f);
    }
}

// ---------------------------------------------------------------------------
// out conv via MFMA (LDS-free): y2b = outwB@yTB + out_b (bf16 channel-major)
__global__ __launch_bounds__(256) void k_outm(const __bf16* __restrict__ yTB,
                                              const __bf16* __restrict__ outwB,
                                              const float* __restrict__ outb,
                                              __bf16* __restrict__ y2b) {
  const int n = blockIdx.y;
  const int px0 = blockIdx.x * 64;
  const int tid = threadIdx.x;
  const int w = tid >> 6, lane = tid & 63;
  const int l15 = lane & 15, lg = lane >> 4;
  const int o0 = w * 64;
  f32x4 acc[4][4];
#pragma unroll
  for (int i = 0; i < 4; ++i)
#pragma unroll
    for (int j = 0; j < 4; ++j) acc[i][j] = (f32x4){0, 0, 0, 0};

  const __bf16* yRow = yTB + ((size_t)n * HW + px0) * 128;
#pragma unroll
  for (int s = 0; s < 4; ++s) {
    bf16x8 a[4], b[4];
#pragma unroll
    for (int t = 0; t < 4; ++t) {
      a[t] = ldb8(&outwB[(size_t)(o0 + t * 16 + l15) * 128 + s * 32 + lg * 8]);
      b[t] = ldb8(&yRow[(size_t)(t * 16 + l15) * 128 + s * 32 + lg * 8]);
    }
#pragma unroll
    for (int i = 0; i < 4; ++i)
#pragma unroll
      for (int j = 0; j < 4; ++j) acc[i][j] = MFMA16(a[i], b[j], acc[i][j]);
  }
#pragma unroll
  for (int i = 0; i < 4; ++i)
#pragma unroll
    for (int r = 0; r < 4; ++r) {
      int o = o0 + i * 16 + lg * 4 + r;
      float bb = outb[o];
      __bf16* dst = y2b + ((size_t)n * CCH + o) * HW + px0;
#pragma unroll
      for (int j = 0; j < 4; ++j)
        dst[j * 16 + l15] = (__bf16)(acc[i][j][r] + bb);
    }
}

// ---------------------------------------------------------------------------
__global__ __launch_bounds__(256) void k_c2p(const __bf16* __restrict__ coef1,
                                             const float* __restrict__ w,
                                             float* __restrict__ part) {
  const int n = blockIdx.y;
  const int kc = blockIdx.z;
  const int p = blockIdx.x * 256 + threadIdx.x;
  const int px = p & 63, py = p >> 6;
  float acc[16];
#pragma unroll
  for (int o = 0; o < 16; ++o) acc[o] = 0.f;
  const __bf16* base = coef1 + (size_t)n * CCH * HW + (size_t)kc * 64 * HW;
  for (int c = 0; c < 64; ++c) {
    const __bf16* img = base + (size_t)c * HW;
    float v[9];
#pragma unroll
    for (int dy = -1; dy <= 1; ++dy)
#pragma unroll
      for (int dx = -1; dx <= 1; ++dx) {
        int yy = py + dy, xx = px + dx;
        bool ok = ((unsigned)yy < 64u) && ((unsigned)xx < 64u);
        v[(dy + 1) * 3 + dx + 1] = ok ? (float)img[yy * 64 + xx] : 0.f;
      }
    const int cg = kc * 64 + c;
#pragma unroll
    for (int o = 0; o < 16; ++o) {
      const float* wp = w + ((size_t)o * CCH + cg) * 9;
      float a = acc[o];
      a = fmaf(wp[0], v[0], a); a = fmaf(wp[1], v[1], a); a = fmaf(wp[2], v[2], a);
      a = fmaf(wp[3], v[3], a); a = fmaf(wp[4], v[4], a); a = fmaf(wp[5], v[5], a);
      a = fmaf(wp[6], v[6], a); a = fmaf(wp[7], v[7], a); a = fmaf(wp[8], v[8], a);
      acc[o] = a;
    }
  }
  float* dst = part + (((size_t)kc * 4 + n) * 16) * HW + p;
#pragma unroll
  for (int o = 0; o < 16; ++o) dst[(size_t)o * HW] = acc[o];
}

__global__ __launch_bounds__(256) void k_c2r(const float* __restrict__ part,
                                             const float* __restrict__ bias,
                                             float* __restrict__ c2o) {
  const int n = blockIdx.y;
  const int p = blockIdx.x * 256 + threadIdx.x;
#pragma unroll
  for (int o = 0; o < 16; ++o) {
    float s = bias[o];
#pragma unroll
    for (int kc = 0; kc < 4; ++kc)
      s += part[(((size_t)kc * 4 + n) * 16 + o) * HW + p];
    c2o[((size_t)n * 16 + o) * HW + p] = fmaxf(s, 0.f);
  }
}

// ---------------------------------------------------------------------------
__global__ __launch_bounds__(256) void k_c3(const float* __restrict__ c2o,
                                            const float* __restrict__ w,
                                            const float* __restrict__ bias,
                                            float* __restrict__ c3o) {
  const int n = blockIdx.y;
  const int p = blockIdx.x * 256 + threadIdx.x;
  const int px = p & 63, py = p >> 6;
  float acc[3] = {bias[0], bias[1], bias[2]};
  for (int c = 0; c < 16; ++c) {
    const float* img = c2o + ((size_t)n * 16 + c) * HW;
    float v[9];
#pragma unroll
    for (int dy = -1; dy <= 1; ++dy)
#pragma unroll
      for (int dx = -1; dx <= 1; ++dx) {
        int yy = py + dy, xx = px + dx;
        bool ok = ((unsigned)yy < 64u) && ((unsigned)xx < 64u);
        v[(dy + 1) * 3 + dx + 1] = ok ? img[yy * 64 + xx] : 0.f;
      }
#pragma unroll
    for (int o = 0; o < 3; ++o) {
      const float* wp = w + ((size_t)o * 16 + c) * 9;
      float a = acc[o];
      a = fmaf(wp[0], v[0], a); a = fmaf(wp[1], v[1], a); a = fmaf(wp[2], v[2], a);
      a = fmaf(wp[3], v[3], a); a = fmaf(wp[4], v[4], a); a = fmaf(wp[5], v[5], a);
      a = fmaf(wp[6], v[6], a); a = fmaf(wp[7], v[7], a); a = fmaf(wp[8], v[8], a);
      acc[o] = a;
    }
  }
#pragma unroll
  for (int o = 0; o < 3; ++o)
    c3o[((size_t)n * 3 + o) * HW + p] = fmaxf(acc[o], 0.f);
}

// ---------------------------------------------------------------------------
__global__ __launch_bounds__(256) void k_c4f(const float* __restrict__ c3o,
                                             const float* __restrict__ w4,
                                             const float* __restrict__ b4,
                                             const float* __restrict__ x,
                                             const __bf16* __restrict__ y2b,
                                             float* __restrict__ out0) {
  const int n = blockIdx.y;
  const int cc = blockIdx.z;
  const int p = blockIdx.x * 256 + threadIdx.x;
  const int px = p & 63, py = p >> 6;
  float coef = b4[0];
#pragma unroll
  for (int c = 0; c < 3; ++c) {
    const float* img = c3o + ((size_t)n * 3 + c) * HW;
#pragma unroll
    for (int dy = -1; dy <= 1; ++dy)
#pragma unroll
      for (int dx = -1; dx <= 1; ++dx) {
        int yy = py + dy, xx = px + dx;
        bool ok = ((unsigned)yy < 64u) && ((unsigned)xx < 64u);
        float v = ok ? img[yy * 64 + xx] : 0.f;
        coef = fmaf(w4[c * 9 + (dy + 1) * 3 + dx + 1], v, coef);
      }
  }
  const size_t base = ((size_t)n * CCH + cc * 64) * HW + p;
#pragma unroll 8
  for (int c = 0; c < 64; ++c) {
    size_t a = base + (size_t)c * HW;
    out0[a] = x[a] + coef * (float)y2b[a];
  }
}

// ---------------------------------------------------------------------------
extern "C" void kernel_launch(void* const* d_in, const int* in_sizes, int n_in,
                              void* d_out, int out_size, void* d_ws, size_t ws_size,
                              hipStream_t stream) {
  (void)in_sizes; (void)n_in; (void)out_size; (void)ws_size;
  const float* x     = (const float*)d_in[0];
  const float* x_ref = (const float*)d_in[1];
  const float* g_w   = (const float*)d_in[2];
  const float* g_b   = (const float*)d_in[3];
  const float* th_w  = (const float*)d_in[4];
  const float* th_b  = (const float*)d_in[5];
  const float* ph_w  = (const float*)d_in[6];
  const float* ph_b  = (const float*)d_in[7];
  const float* out_w = (const float*)d_in[8];
  const float* out_b = (const float*)d_in[9];
  const float* c1_w  = (const float*)d_in[10];
  const float* c1_b  = (const float*)d_in[11];
  const float* c2_w  = (const float*)d_in[12];
  const float* c2_b  = (const float*)d_in[13];
  const float* c3_w  = (const float*)d_in[14];
  const float* c3_b  = (const float*)d_in[15];
  const float* c4_w  = (const float*)d_in[16];
  const float* c4_b  = (const float*)d_in[17];

  float* ws = (float*)d_ws;
  // region plan (float offsets):
  //  xB     [0, 2M)        bf16 x transposed [n][px][256]
  //  yTB    [2M, 3M)       bf16 y [n][px][128]
  //  thB    [3M, 4M)       } dead after attn -> coef1B [3M, 5M)
  //  phB    [4M, 5M)       }
  //  gB     [5M, 6M)       } dead after attn -> y2b [5M, 7M)
  //  c2p    [7M, 8M) ; c2o [8M, 8.25M) ; c3o, rowsum(unused), prep arrays after
  __bf16* xB   = (__bf16*)(ws + 0);
  __bf16* yTB  = (__bf16*)(ws + 2097152);
  __bf16* thB  = (__bf16*)(ws + 3145728);
  __bf16* phB  = (__bf16*)(ws + 4194304);
  __bf16* gBf  = (__bf16*)(ws + 5242880);
  __bf16* coef1B = (__bf16*)(ws + 3145728);  // aliases thB+phB (dead)
  __bf16* y2b    = (__bf16*)(ws + 5242880);  // aliases gB (dead)
  float* c2p   = ws + 7340032;
  float* c2o   = ws + 8388608;
  float* c3o   = ws + 8650752;
  __bf16* c1xB = (__bf16*)(ws + 8716288);
  __bf16* W2B  = (__bf16*)(ws + 8749056);
  __bf16* outwB= (__bf16*)(ws + 8765440);
  float* bias2 = ws + 8781824;

  float* out0 = (float*)d_out;
  float* P    = out0 + 4194304;

  dim3 blk(256);
  k_projT<<<dim3(64, 4), blk, 0, stream>>>(x, th_w, th_b, thB, xB);
  k_projPG<<<dim3(64, 4), blk, 0, stream>>>(x_ref, ph_w, g_w, ph_b, g_b, phB, gBf);
  k_prep<<<dim3(512), blk, 0, stream>>>(c1_w, c1_b, out_w, out_b, c1xB, W2B, outwB, bias2);
  k_attn<<<dim3(64, 4), dim3(512), 0, stream>>>(thB, phB, gBf, P, yTB);
  k_c1m<<<dim3(64, 4), blk, 0, stream>>>(xB, yTB, c1xB, W2B, bias2, coef1B);
  k_outm<<<dim3(64, 4), blk, 0, stream>>>(yTB, outwB, out_b, y2b);
  k_c2p<<<dim3(16, 4, 4), blk, 0, stream>>>(coef1B, c2_w, c2p);
  k_c2r<<<dim3(16, 4), blk, 0, stream>>>(c2p, c2_b, c2o);
  k_c3<<<dim3(16, 4), blk, 0, stream>>>(c2o, c3_w, c3_b, c3o);
  k_c4f<<<dim3(16, 4, 4), blk, 0, stream>>>(c3o, c4_w, c4_b, x, y2b, out0);
}